// Round 1
// baseline (602.001 us; speedup 1.0000x reference)
//
#include <hip/hip_runtime.h>

#define N_NODES 50000
#define N_EDGES 800000
#define DIN     128
#define HD      128   // H * D_HEAD
#define NHEAD   8
#define DHEAD   16

// ---------------------------------------------------------------------------
// Stage 1: Q/K/V projection.  8 nodes per block, 128 threads (one per output
// column). h rows staged in LDS (broadcast reads), W columns coalesced.
// ---------------------------------------------------------------------------
__global__ __launch_bounds__(128) void proj_kernel(
    const float* __restrict__ h,
    const float* __restrict__ Wq, const float* __restrict__ bq,
    const float* __restrict__ Wk, const float* __restrict__ bk,
    const float* __restrict__ Wv, const float* __restrict__ bv,
    float* __restrict__ Q, float* __restrict__ K, float* __restrict__ V)
{
    const int t  = threadIdx.x;        // output column 0..127
    const int n0 = blockIdx.x * 8;     // first node of this block

    __shared__ float hs[8][DIN];
    #pragma unroll
    for (int j = 0; j < 8; ++j) {
        int n = n0 + j;
        hs[j][t] = (n < N_NODES) ? h[(size_t)n * DIN + t] : 0.f;
    }
    __syncthreads();

    float qa[8], ka[8], va[8];
    const float bqv = bq[t], bkv = bk[t], bvv = bv[t];
    #pragma unroll
    for (int j = 0; j < 8; ++j) { qa[j] = bqv; ka[j] = bkv; va[j] = bvv; }

    for (int kk = 0; kk < DIN; ++kk) {
        const float wq = Wq[kk * HD + t];
        const float wk = Wk[kk * HD + t];
        const float wv = Wv[kk * HD + t];
        #pragma unroll
        for (int j = 0; j < 8; ++j) {
            const float hv = hs[j][kk];
            qa[j] = fmaf(hv, wq, qa[j]);
            ka[j] = fmaf(hv, wk, ka[j]);
            va[j] = fmaf(hv, wv, va[j]);
        }
    }

    #pragma unroll
    for (int j = 0; j < 8; ++j) {
        int n = n0 + j;
        if (n < N_NODES) {
            Q[(size_t)n * HD + t] = qa[j];
            K[(size_t)n * HD + t] = ka[j];
            V[(size_t)n * HD + t] = va[j];
        }
    }
}

// ---------------------------------------------------------------------------
// Stage 2: per-edge score + scatter.  128 threads per edge (lane = h*16+d),
// 2 edges per 256-thread block.  16-lane shuffle reduce for the dot product.
// ---------------------------------------------------------------------------
__global__ __launch_bounds__(256) void edge_kernel(
    const float* __restrict__ Q, const float* __restrict__ K,
    const float* __restrict__ V,
    const int* __restrict__ src, const int* __restrict__ dst,
    float* __restrict__ out, float* __restrict__ z)
{
    const int eid = blockIdx.x * 2 + (threadIdx.x >> 7);
    if (eid >= N_EDGES) return;
    const int t = threadIdx.x & 127;   // h*16 + d

    const int s = src[eid];
    const int d = dst[eid];

    const float kv = K[(size_t)s * HD + t];
    const float qv = Q[(size_t)d * HD + t];
    float p = kv * qv;
    // reduce across the 16 lanes of this head (lanes are contiguous in-wave)
    p += __shfl_xor(p, 1, 16);
    p += __shfl_xor(p, 2, 16);
    p += __shfl_xor(p, 4, 16);
    p += __shfl_xor(p, 8, 16);

    float sc = p * 0.25f;                       // / SCALE (=4)
    sc = fminf(fmaxf(sc, -5.f), 5.f);
    const float score = __expf(sc);

    const float val = V[(size_t)s * HD + t] * score;
    atomicAdd(&out[(size_t)d * HD + t], val);
    if ((t & 15) == 0)
        atomicAdd(&z[(size_t)d * NHEAD + (t >> 4)], score);
}

// ---------------------------------------------------------------------------
// Stage 3: normalize by segment-summed score.
// ---------------------------------------------------------------------------
__global__ __launch_bounds__(256) void finalize_kernel(
    float* __restrict__ out, const float* __restrict__ z)
{
    const int i = blockIdx.x * 256 + threadIdx.x;
    if (i < N_NODES * HD) {
        const int n  = i >> 7;
        const int hh = (i >> 4) & 7;
        out[i] = out[i] / (z[n * NHEAD + hh] + 1e-6f);
    }
}

// ---------------------------------------------------------------------------
extern "C" void kernel_launch(void* const* d_in, const int* in_sizes, int n_in,
                              void* d_out, int out_size, void* d_ws, size_t ws_size,
                              hipStream_t stream)
{
    const float* h  = (const float*)d_in[0];
    const float* Wq = (const float*)d_in[1];
    const float* bq = (const float*)d_in[2];
    const float* Wk = (const float*)d_in[3];
    const float* bk = (const float*)d_in[4];
    const float* Wv = (const float*)d_in[5];
    const float* bv = (const float*)d_in[6];
    const int*   src = (const int*)d_in[7];
    const int*   dst = (const int*)d_in[8];
    float* out = (float*)d_out;

    // workspace layout: Q | K | V | z   (3*25.6 MB + 1.6 MB = 78.4 MB)
    float* Q = (float*)d_ws;
    float* K = Q + (size_t)N_NODES * HD;
    float* V = K + (size_t)N_NODES * HD;
    float* z = V + (size_t)N_NODES * HD;

    hipMemsetAsync(d_out, 0, (size_t)N_NODES * HD * sizeof(float), stream);
    hipMemsetAsync(z,     0, (size_t)N_NODES * NHEAD * sizeof(float), stream);

    proj_kernel<<<(N_NODES + 7) / 8, 128, 0, stream>>>(
        h, Wq, bq, Wk, bk, Wv, bv, Q, K, V);

    edge_kernel<<<(N_EDGES + 1) / 2, 256, 0, stream>>>(
        Q, K, V, src, dst, out, z);

    finalize_kernel<<<(N_NODES * HD + 255) / 256, 256, 0, stream>>>(out, z);
}

// Round 2
// 384.094 us; speedup vs baseline: 1.5673x; 1.5673x over previous
//
#include <hip/hip_runtime.h>

#define N_NODES 50000
#define N_EDGES 800000
#define DIN     128
#define HD      128   // H * D_HEAD
#define NHEAD   8
#define DHEAD   16

#define M_PAD   50176             // 49 * 1024, scan-padded node count
#define NB_SCAN 49

// ---------------------------------------------------------------------------
// Stage 1: Q/K/V projection.  8 nodes per block, 128 threads (one per output
// column). h rows staged in LDS (broadcast reads), W columns coalesced.
// ---------------------------------------------------------------------------
__global__ __launch_bounds__(128) void proj_kernel(
    const float* __restrict__ h,
    const float* __restrict__ Wq, const float* __restrict__ bq,
    const float* __restrict__ Wk, const float* __restrict__ bk,
    const float* __restrict__ Wv, const float* __restrict__ bv,
    float* __restrict__ Q, float* __restrict__ K, float* __restrict__ V)
{
    const int t  = threadIdx.x;
    const int n0 = blockIdx.x * 8;

    __shared__ float hs[8][DIN];
    #pragma unroll
    for (int j = 0; j < 8; ++j) {
        int n = n0 + j;
        hs[j][t] = (n < N_NODES) ? h[(size_t)n * DIN + t] : 0.f;
    }
    __syncthreads();

    float qa[8], ka[8], va[8];
    const float bqv = bq[t], bkv = bk[t], bvv = bv[t];
    #pragma unroll
    for (int j = 0; j < 8; ++j) { qa[j] = bqv; ka[j] = bkv; va[j] = bvv; }

    for (int kk = 0; kk < DIN; ++kk) {
        const float wq = Wq[kk * HD + t];
        const float wk = Wk[kk * HD + t];
        const float wv = Wv[kk * HD + t];
        #pragma unroll
        for (int j = 0; j < 8; ++j) {
            const float hv = hs[j][kk];
            qa[j] = fmaf(hv, wq, qa[j]);
            ka[j] = fmaf(hv, wk, ka[j]);
            va[j] = fmaf(hv, wv, va[j]);
        }
    }

    #pragma unroll
    for (int j = 0; j < 8; ++j) {
        int n = n0 + j;
        if (n < N_NODES) {
            Q[(size_t)n * HD + t] = qa[j];
            K[(size_t)n * HD + t] = ka[j];
            V[(size_t)n * HD + t] = va[j];
        }
    }
}

// ---------------------------------------------------------------------------
// CSR build: histogram -> 3-kernel exclusive scan -> scatter
// ---------------------------------------------------------------------------
__global__ __launch_bounds__(256) void hist_kernel(
    const int* __restrict__ dst, int* __restrict__ counts)
{
    const int e = blockIdx.x * 256 + threadIdx.x;
    if (e < N_EDGES) atomicAdd(&counts[dst[e]], 1);
}

__global__ __launch_bounds__(256) void scan_blocks_kernel(
    const int* __restrict__ counts, int* __restrict__ row_start,
    int* __restrict__ blockSums)
{
    __shared__ int s[256];
    const int tid  = threadIdx.x;
    const int base = blockIdx.x * 1024 + tid * 4;

    const int v0 = counts[base], v1 = counts[base + 1];
    const int v2 = counts[base + 2], v3 = counts[base + 3];
    const int tsum = v0 + v1 + v2 + v3;
    s[tid] = tsum;
    __syncthreads();
    for (int off = 1; off < 256; off <<= 1) {
        int x = (tid >= off) ? s[tid - off] : 0;
        __syncthreads();
        s[tid] += x;
        __syncthreads();
    }
    const int excl = s[tid] - tsum;
    row_start[base]     = excl;
    row_start[base + 1] = excl + v0;
    row_start[base + 2] = excl + v0 + v1;
    row_start[base + 3] = excl + v0 + v1 + v2;
    if (tid == 255) blockSums[blockIdx.x] = s[255];
}

__global__ __launch_bounds__(64) void scan_sums_kernel(
    const int* __restrict__ blockSums, int* __restrict__ blockOff)
{
    const int lane = threadIdx.x;
    int v = (lane < NB_SCAN) ? blockSums[lane] : 0;
    const int orig = v;
    for (int off = 1; off < 64; off <<= 1) {
        int x = __shfl_up(v, off);
        if (lane >= off) v += x;
    }
    blockOff[lane] = v - orig;
}

__global__ __launch_bounds__(256) void add_offsets_kernel(
    int* __restrict__ row_start, const int* __restrict__ blockOff)
{
    const int off  = blockOff[blockIdx.x];
    const int base = blockIdx.x * 1024 + threadIdx.x * 4;
    row_start[base]     += off;
    row_start[base + 1] += off;
    row_start[base + 2] += off;
    row_start[base + 3] += off;
}

__global__ __launch_bounds__(256) void scatter_kernel(
    const int* __restrict__ src, const int* __restrict__ dst,
    int* __restrict__ cursor, int* __restrict__ sorted_src)
{
    const int e = blockIdx.x * 256 + threadIdx.x;
    if (e < N_EDGES) {
        const int pos = atomicAdd(&cursor[dst[e]], 1);
        sorted_src[pos] = src[e];
    }
}

// ---------------------------------------------------------------------------
// Stage 2 (gather): one 128-thread group per destination node.  Q row kept in
// registers, in-edges gathered via CSR, accumulate in registers, single write
// with the z-division fused.  Zero atomics.
// ---------------------------------------------------------------------------
__global__ __launch_bounds__(256) void aggregate_kernel(
    const float* __restrict__ Q, const float* __restrict__ K,
    const float* __restrict__ V,
    const int* __restrict__ row_start, const int* __restrict__ sorted_src,
    float* __restrict__ out)
{
    const int node = blockIdx.x * 2 + (threadIdx.x >> 7);
    if (node >= N_NODES) return;
    const int t = threadIdx.x & 127;           // h*16 + d

    const float qv = Q[(size_t)node * HD + t];
    const int beg = row_start[node];
    const int end = row_start[node + 1];

    float acc = 0.f, zacc = 0.f;

    int e = beg;
    for (; e + 1 < end; e += 2) {
        const int s0 = sorted_src[e];
        const int s1 = sorted_src[e + 1];
        const float k0 = K[(size_t)s0 * HD + t];
        const float k1 = K[(size_t)s1 * HD + t];
        const float w0 = V[(size_t)s0 * HD + t];
        const float w1 = V[(size_t)s1 * HD + t];

        float p0 = k0 * qv;
        float p1 = k1 * qv;
        p0 += __shfl_xor(p0, 1, 16);  p1 += __shfl_xor(p1, 1, 16);
        p0 += __shfl_xor(p0, 2, 16);  p1 += __shfl_xor(p1, 2, 16);
        p0 += __shfl_xor(p0, 4, 16);  p1 += __shfl_xor(p1, 4, 16);
        p0 += __shfl_xor(p0, 8, 16);  p1 += __shfl_xor(p1, 8, 16);

        const float s0c = __expf(fminf(fmaxf(p0 * 0.25f, -5.f), 5.f));
        const float s1c = __expf(fminf(fmaxf(p1 * 0.25f, -5.f), 5.f));
        acc  = fmaf(w0, s0c, acc);
        acc  = fmaf(w1, s1c, acc);
        zacc += s0c + s1c;
    }
    if (e < end) {
        const int s0 = sorted_src[e];
        const float k0 = K[(size_t)s0 * HD + t];
        float p0 = k0 * qv;
        p0 += __shfl_xor(p0, 1, 16);
        p0 += __shfl_xor(p0, 2, 16);
        p0 += __shfl_xor(p0, 4, 16);
        p0 += __shfl_xor(p0, 8, 16);
        const float s0c = __expf(fminf(fmaxf(p0 * 0.25f, -5.f), 5.f));
        acc  = fmaf(V[(size_t)s0 * HD + t], s0c, acc);
        zacc += s0c;
    }

    out[(size_t)node * HD + t] = acc / (zacc + 1e-6f);
}

// ---------------------------------------------------------------------------
extern "C" void kernel_launch(void* const* d_in, const int* in_sizes, int n_in,
                              void* d_out, int out_size, void* d_ws, size_t ws_size,
                              hipStream_t stream)
{
    const float* h  = (const float*)d_in[0];
    const float* Wq = (const float*)d_in[1];
    const float* bq = (const float*)d_in[2];
    const float* Wk = (const float*)d_in[3];
    const float* bk = (const float*)d_in[4];
    const float* Wv = (const float*)d_in[5];
    const float* bv = (const float*)d_in[6];
    const int*   src = (const int*)d_in[7];
    const int*   dst = (const int*)d_in[8];
    float* out = (float*)d_out;

    // workspace layout
    float* Q = (float*)d_ws;
    float* K = Q + (size_t)N_NODES * HD;
    float* V = K + (size_t)N_NODES * HD;
    int* counts     = (int*)(V + (size_t)N_NODES * HD);
    int* row_start  = counts + M_PAD;
    int* cursor     = row_start + M_PAD;
    int* blockSums  = cursor + M_PAD;
    int* blockOff   = blockSums + 64;
    int* sorted_src = blockOff + 64;

    hipMemsetAsync(counts, 0, M_PAD * sizeof(int), stream);

    proj_kernel<<<(N_NODES + 7) / 8, 128, 0, stream>>>(
        h, Wq, bq, Wk, bk, Wv, bv, Q, K, V);

    hist_kernel<<<(N_EDGES + 255) / 256, 256, 0, stream>>>(dst, counts);
    scan_blocks_kernel<<<NB_SCAN, 256, 0, stream>>>(counts, row_start, blockSums);
    scan_sums_kernel<<<1, 64, 0, stream>>>(blockSums, blockOff);
    add_offsets_kernel<<<NB_SCAN, 256, 0, stream>>>(row_start, blockOff);

    hipMemcpyAsync(cursor, row_start, M_PAD * sizeof(int),
                   hipMemcpyDeviceToDevice, stream);
    scatter_kernel<<<(N_EDGES + 255) / 256, 256, 0, stream>>>(
        src, dst, cursor, sorted_src);

    aggregate_kernel<<<(N_NODES + 1) / 2, 256, 0, stream>>>(
        Q, K, V, row_start, sorted_src, out);
}

// Round 3
// 319.762 us; speedup vs baseline: 1.8827x; 1.2012x over previous
//
#include <hip/hip_runtime.h>
#include <hip/hip_bf16.h>

#define N_NODES 50000
#define N_EDGES 800000
#define DIN     128
#define HD      128   // H * D_HEAD
#define NHEAD   8
#define DHEAD   16

#define M_PAD   50176             // 49 * 1024, scan-padded node count
#define NB_SCAN 49

typedef __attribute__((ext_vector_type(8))) short short8;   // 8 bf16
typedef __attribute__((ext_vector_type(4))) float float4v;  // 4 fp32 acc

static __device__ __forceinline__ unsigned short f2bf_bits(float f) {
    __hip_bfloat16 b = __float2bfloat16(f);
    return *reinterpret_cast<unsigned short*>(&b);
}

// ---------------------------------------------------------------------------
// h (fp32) -> bf16 bits, 4 elements per thread
// ---------------------------------------------------------------------------
__global__ __launch_bounds__(256) void cvt_h_kernel(
    const float* __restrict__ h, unsigned short* __restrict__ hb)
{
    const int i = (blockIdx.x * 256 + threadIdx.x) * 4;
    if (i < N_NODES * DIN) {
        const float4 v = *(const float4*)(h + i);
        ushort4 o;
        o.x = f2bf_bits(v.x); o.y = f2bf_bits(v.y);
        o.z = f2bf_bits(v.z); o.w = f2bf_bits(v.w);
        *(ushort4*)(hb + i) = o;
    }
}

// ---------------------------------------------------------------------------
// W[k][n] (fp32) -> Wt[mat][n][k] (bf16 bits).  Tiny (3*16K elements).
// ---------------------------------------------------------------------------
__global__ __launch_bounds__(128) void cvt_w_kernel(
    const float* __restrict__ Wq, const float* __restrict__ Wk,
    const float* __restrict__ Wv, unsigned short* __restrict__ Wt)
{
    const int mat = blockIdx.x >> 7;
    const int n   = blockIdx.x & 127;
    const int k   = threadIdx.x;
    const float* W = (mat == 0) ? Wq : (mat == 1) ? Wk : Wv;
    Wt[mat * (DIN * HD) + n * DIN + k] = f2bf_bits(W[k * HD + n]);
}

// ---------------------------------------------------------------------------
// Stage 1: Q/K/V projection via bf16 MFMA.  Block = 256 thr = 4 waves; each
// wave computes 32 rows x 128 cols (2 row-tiles x 8 col-tiles of 16x16).
// blockIdx.y picks Q/K/V.  Q written fp32; K/V written bf16 interleaved
// per node: KV[node*256 + 0..127] = K row, [128..255] = V row.
// ---------------------------------------------------------------------------
__global__ __launch_bounds__(256) void proj_mfma_kernel(
    const unsigned short* __restrict__ hb,
    const unsigned short* __restrict__ Wt,
    const float* __restrict__ bq, const float* __restrict__ bk,
    const float* __restrict__ bv,
    float* __restrict__ Qf, __hip_bfloat16* __restrict__ KV)
{
    const int mat  = blockIdx.y;            // 0=Q, 1=K, 2=V
    const int wave = threadIdx.x >> 6;
    const int lane = threadIdx.x & 63;
    const int quad = lane >> 4;
    const int l16  = lane & 15;

    const int rowBase = blockIdx.x * 128 + wave * 32;
    const unsigned short* wbase = Wt + mat * (DIN * HD);
    const float* bias = (mat == 0) ? bq : (mat == 1) ? bk : bv;

    float4v acc[2][8];
    #pragma unroll
    for (int rt = 0; rt < 2; ++rt)
        #pragma unroll
        for (int ct = 0; ct < 8; ++ct)
            acc[rt][ct] = (float4v){0.f, 0.f, 0.f, 0.f};

    // A-fragment row indices (clamped; duplicate reads are harmless)
    int r0 = rowBase + l16;       if (r0 >= N_NODES) r0 = N_NODES - 1;
    int r1 = rowBase + 16 + l16;  if (r1 >= N_NODES) r1 = N_NODES - 1;

    for (int kc = 0; kc < 4; ++kc) {
        const int ko = kc * 32 + quad * 8;
        const short8 a0 = *(const short8*)(hb + (size_t)r0 * DIN + ko);
        const short8 a1 = *(const short8*)(hb + (size_t)r1 * DIN + ko);
        #pragma unroll
        for (int ct = 0; ct < 8; ++ct) {
            const short8 b = *(const short8*)(wbase + (ct * 16 + l16) * DIN + ko);
            acc[0][ct] = __builtin_amdgcn_mfma_f32_16x16x32_bf16(a0, b, acc[0][ct], 0, 0, 0);
            acc[1][ct] = __builtin_amdgcn_mfma_f32_16x16x32_bf16(a1, b, acc[1][ct], 0, 0, 0);
        }
    }

    // Epilogue: D[row=quad*4+r][col=lane&15] per tile, + bias, store.
    #pragma unroll
    for (int ct = 0; ct < 8; ++ct) {
        const int col = ct * 16 + l16;
        const float bcol = bias[col];
        #pragma unroll
        for (int rt = 0; rt < 2; ++rt) {
            #pragma unroll
            for (int r = 0; r < 4; ++r) {
                const int row = rowBase + rt * 16 + quad * 4 + r;
                if (row < N_NODES) {
                    const float v = acc[rt][ct][r] + bcol;
                    if (mat == 0) {
                        Qf[(size_t)row * HD + col] = v;
                    } else {
                        KV[(size_t)row * 256 + (mat == 2 ? 128 : 0) + col] =
                            __float2bfloat16(v);
                    }
                }
            }
        }
    }
}

// ---------------------------------------------------------------------------
// CSR build: histogram -> 3-kernel exclusive scan -> scatter
// ---------------------------------------------------------------------------
__global__ __launch_bounds__(256) void hist_kernel(
    const int* __restrict__ dst, int* __restrict__ counts)
{
    const int e = blockIdx.x * 256 + threadIdx.x;
    if (e < N_EDGES) atomicAdd(&counts[dst[e]], 1);
}

__global__ __launch_bounds__(256) void scan_blocks_kernel(
    const int* __restrict__ counts, int* __restrict__ row_start,
    int* __restrict__ blockSums)
{
    __shared__ int s[256];
    const int tid  = threadIdx.x;
    const int base = blockIdx.x * 1024 + tid * 4;

    const int v0 = counts[base], v1 = counts[base + 1];
    const int v2 = counts[base + 2], v3 = counts[base + 3];
    const int tsum = v0 + v1 + v2 + v3;
    s[tid] = tsum;
    __syncthreads();
    for (int off = 1; off < 256; off <<= 1) {
        int x = (tid >= off) ? s[tid - off] : 0;
        __syncthreads();
        s[tid] += x;
        __syncthreads();
    }
    const int excl = s[tid] - tsum;
    row_start[base]     = excl;
    row_start[base + 1] = excl + v0;
    row_start[base + 2] = excl + v0 + v1;
    row_start[base + 3] = excl + v0 + v1 + v2;
    if (tid == 255) blockSums[blockIdx.x] = s[255];
}

__global__ __launch_bounds__(64) void scan_sums_kernel(
    const int* __restrict__ blockSums, int* __restrict__ blockOff)
{
    const int lane = threadIdx.x;
    int v = (lane < NB_SCAN) ? blockSums[lane] : 0;
    const int orig = v;
    for (int off = 1; off < 64; off <<= 1) {
        int x = __shfl_up(v, off);
        if (lane >= off) v += x;
    }
    blockOff[lane] = v - orig;
}

__global__ __launch_bounds__(256) void add_offsets_kernel(
    int* __restrict__ row_start, const int* __restrict__ blockOff)
{
    const int off  = blockOff[blockIdx.x];
    const int base = blockIdx.x * 1024 + threadIdx.x * 4;
    row_start[base]     += off;
    row_start[base + 1] += off;
    row_start[base + 2] += off;
    row_start[base + 3] += off;
}

__global__ __launch_bounds__(256) void scatter_kernel(
    const int* __restrict__ src, const int* __restrict__ dst,
    int* __restrict__ cursor, int* __restrict__ sorted_src)
{
    const int e = blockIdx.x * 256 + threadIdx.x;
    if (e < N_EDGES) {
        const int pos = atomicAdd(&cursor[dst[e]], 1);
        sorted_src[pos] = src[e];
    }
}

// ---------------------------------------------------------------------------
// Stage 2 (gather): 128 threads per destination node, 4-deep edge unroll for
// memory-level parallelism.  Q fp32 (read once per node), K/V bf16 gathers.
// ---------------------------------------------------------------------------
__global__ __launch_bounds__(256) void aggregate_kernel(
    const float* __restrict__ Qf, const __hip_bfloat16* __restrict__ KV,
    const int* __restrict__ row_start, const int* __restrict__ sorted_src,
    float* __restrict__ out)
{
    const int node = blockIdx.x * 2 + (threadIdx.x >> 7);
    if (node >= N_NODES) return;
    const int t = threadIdx.x & 127;           // h*16 + d

    const float qv = Qf[(size_t)node * HD + t];
    const int beg = row_start[node];
    const int end = row_start[node + 1];

    float acc = 0.f, zacc = 0.f;

    int e = beg;
    for (; e + 3 < end; e += 4) {
        const int s0 = sorted_src[e];
        const int s1 = sorted_src[e + 1];
        const int s2 = sorted_src[e + 2];
        const int s3 = sorted_src[e + 3];
        const float k0 = __bfloat162float(KV[(size_t)s0 * 256 + t]);
        const float k1 = __bfloat162float(KV[(size_t)s1 * 256 + t]);
        const float k2 = __bfloat162float(KV[(size_t)s2 * 256 + t]);
        const float k3 = __bfloat162float(KV[(size_t)s3 * 256 + t]);
        const float w0 = __bfloat162float(KV[(size_t)s0 * 256 + 128 + t]);
        const float w1 = __bfloat162float(KV[(size_t)s1 * 256 + 128 + t]);
        const float w2 = __bfloat162float(KV[(size_t)s2 * 256 + 128 + t]);
        const float w3 = __bfloat162float(KV[(size_t)s3 * 256 + 128 + t]);

        float p0 = k0 * qv, p1 = k1 * qv, p2 = k2 * qv, p3 = k3 * qv;
        #pragma unroll
        for (int m = 1; m < 16; m <<= 1) {
            p0 += __shfl_xor(p0, m, 16);
            p1 += __shfl_xor(p1, m, 16);
            p2 += __shfl_xor(p2, m, 16);
            p3 += __shfl_xor(p3, m, 16);
        }
        const float c0 = __expf(fminf(fmaxf(p0 * 0.25f, -5.f), 5.f));
        const float c1 = __expf(fminf(fmaxf(p1 * 0.25f, -5.f), 5.f));
        const float c2 = __expf(fminf(fmaxf(p2 * 0.25f, -5.f), 5.f));
        const float c3 = __expf(fminf(fmaxf(p3 * 0.25f, -5.f), 5.f));
        acc = fmaf(w0, c0, acc); acc = fmaf(w1, c1, acc);
        acc = fmaf(w2, c2, acc); acc = fmaf(w3, c3, acc);
        zacc += (c0 + c1) + (c2 + c3);
    }
    for (; e < end; ++e) {
        const int s0 = sorted_src[e];
        const float k0 = __bfloat162float(KV[(size_t)s0 * 256 + t]);
        const float w0 = __bfloat162float(KV[(size_t)s0 * 256 + 128 + t]);
        float p0 = k0 * qv;
        #pragma unroll
        for (int m = 1; m < 16; m <<= 1) p0 += __shfl_xor(p0, m, 16);
        const float c0 = __expf(fminf(fmaxf(p0 * 0.25f, -5.f), 5.f));
        acc = fmaf(w0, c0, acc);
        zacc += c0;
    }

    out[(size_t)node * HD + t] = acc / (zacc + 1e-6f);
}

// ---------------------------------------------------------------------------
extern "C" void kernel_launch(void* const* d_in, const int* in_sizes, int n_in,
                              void* d_out, int out_size, void* d_ws, size_t ws_size,
                              hipStream_t stream)
{
    const float* h  = (const float*)d_in[0];
    const float* Wq = (const float*)d_in[1];
    const float* bq = (const float*)d_in[2];
    const float* Wk = (const float*)d_in[3];
    const float* bk = (const float*)d_in[4];
    const float* Wv = (const float*)d_in[5];
    const float* bv = (const float*)d_in[6];
    const int*   src = (const int*)d_in[7];
    const int*   dst = (const int*)d_in[8];
    float* out = (float*)d_out;

    // workspace layout (all 16B-aligned offsets):
    //   Qf   fp32  [50000][128]                 25.6 MB
    //   KV   bf16  [50000][256] (K|V interleave) 25.6 MB
    //   hb   bf16  [50000][128]                 12.8 MB
    //   Wt   bf16  [3][128][128]                 0.1 MB
    //   CSR ints                                  3.8 MB
    float* Qf = (float*)d_ws;
    __hip_bfloat16* KV = (__hip_bfloat16*)(Qf + (size_t)N_NODES * HD);
    unsigned short* hb = (unsigned short*)(KV + (size_t)N_NODES * 256);
    unsigned short* Wt = hb + (size_t)N_NODES * DIN;
    int* counts     = (int*)(Wt + 3 * DIN * HD);
    int* row_start  = counts + M_PAD;
    int* cursor     = row_start + M_PAD;
    int* blockSums  = cursor + M_PAD;
    int* blockOff   = blockSums + 64;
    int* sorted_src = blockOff + 64;

    hipMemsetAsync(counts, 0, M_PAD * sizeof(int), stream);

    cvt_h_kernel<<<(N_NODES * DIN / 4 + 255) / 256, 256, 0, stream>>>(h, hb);
    cvt_w_kernel<<<3 * 128, 128, 0, stream>>>(Wq, Wk, Wv, Wt);

    dim3 pgrid((N_NODES + 127) / 128, 3);
    proj_mfma_kernel<<<pgrid, 256, 0, stream>>>(hb, Wt, bq, bk, bv, Qf, KV);

    hist_kernel<<<(N_EDGES + 255) / 256, 256, 0, stream>>>(dst, counts);
    scan_blocks_kernel<<<NB_SCAN, 256, 0, stream>>>(counts, row_start, blockSums);
    scan_sums_kernel<<<1, 64, 0, stream>>>(blockSums, blockOff);
    add_offsets_kernel<<<NB_SCAN, 256, 0, stream>>>(row_start, blockOff);

    hipMemcpyAsync(cursor, row_start, M_PAD * sizeof(int),
                   hipMemcpyDeviceToDevice, stream);
    scatter_kernel<<<(N_EDGES + 255) / 256, 256, 0, stream>>>(
        src, dst, cursor, sorted_src);

    aggregate_kernel<<<(N_NODES + 1) / 2, 256, 0, stream>>>(
        Qf, KV, row_start, sorted_src, out);
}

// Round 4
// 270.907 us; speedup vs baseline: 2.2222x; 1.1803x over previous
//
#include <hip/hip_runtime.h>
#include <hip/hip_bf16.h>

#define N_NODES 50000
#define N_EDGES 800000
#define DIN     128
#define HD      128   // H * D_HEAD
#define NHEAD   8
#define DHEAD   16

#define M_PAD        50176           // 1024 * 49, scan-padded node count
#define HIST_BLOCKS  3125            // ceil(800000/256)
#define CVTW_BLOCKS  192             // 3*128*128/256
#define PROJ_BLOCKS  391             // ceil(50000/128)
#define SCAT_BLOCKS  3125

typedef __attribute__((ext_vector_type(8))) short short8;   // 8 bf16
typedef __attribute__((ext_vector_type(4))) float float4v;  // 4 fp32 acc

static __device__ __forceinline__ unsigned short f2bf_bits(float f) {
    __hip_bfloat16 b = __float2bfloat16(f);
    return *reinterpret_cast<unsigned short*>(&b);
}
static __device__ __forceinline__ float bfb(short b) {
    return __uint_as_float(((unsigned int)(unsigned short)b) << 16);
}
static __device__ __forceinline__ short8 cvt8(const float* p) {
    const float4 f0 = *(const float4*)p;
    const float4 f1 = *(const float4*)(p + 4);
    short8 r;
    r[0] = (short)f2bf_bits(f0.x); r[1] = (short)f2bf_bits(f0.y);
    r[2] = (short)f2bf_bits(f0.z); r[3] = (short)f2bf_bits(f0.w);
    r[4] = (short)f2bf_bits(f1.x); r[5] = (short)f2bf_bits(f1.y);
    r[6] = (short)f2bf_bits(f1.z); r[7] = (short)f2bf_bits(f1.w);
    return r;
}

// ---------------------------------------------------------------------------
// Node 2: dst-histogram  +  W transpose/convert (independent work, one launch)
// ---------------------------------------------------------------------------
__global__ __launch_bounds__(256) void hist_cvtw_kernel(
    const int* __restrict__ dst,
    const float* __restrict__ Wq, const float* __restrict__ Wk,
    const float* __restrict__ Wv,
    int* __restrict__ counts, unsigned short* __restrict__ Wt)
{
    const int bid = blockIdx.x;
    if (bid < HIST_BLOCKS) {
        const int e = bid * 256 + threadIdx.x;
        if (e < N_EDGES) atomicAdd(&counts[dst[e]], 1);
    } else {
        const int i   = (bid - HIST_BLOCKS) * 256 + threadIdx.x; // < 49152
        const int n   = i & 127;
        const int k   = (i >> 7) & 127;
        const int mat = i >> 14;
        const float* W = (mat == 0) ? Wq : (mat == 1) ? Wk : Wv;
        Wt[mat * (DIN * HD) + n * DIN + k] = f2bf_bits(W[k * HD + n]);
    }
}

// ---------------------------------------------------------------------------
// Node 3: full exclusive scan of counts[0..50175] in ONE block.
// Thread t owns the contiguous range [t*49, t*49+49).
// ---------------------------------------------------------------------------
__global__ __launch_bounds__(1024) void scan_kernel(
    const int* __restrict__ counts, int* __restrict__ cursor)
{
    __shared__ int s[1024];
    const int tid  = threadIdx.x;
    const int base = tid * 49;

    int sum = 0;
    #pragma unroll
    for (int i = 0; i < 49; ++i) sum += counts[base + i];

    s[tid] = sum;
    __syncthreads();
    for (int off = 1; off < 1024; off <<= 1) {
        int x = (tid >= off) ? s[tid - off] : 0;
        __syncthreads();
        s[tid] += x;
        __syncthreads();
    }
    int excl = s[tid] - sum;
    #pragma unroll
    for (int i = 0; i < 49; ++i) {
        cursor[base + i] = excl;
        excl += counts[base + i];
    }
}

// ---------------------------------------------------------------------------
// Node 4: fused  [Q/K/V projection via bf16 MFMA]  +  [edge scatter sort].
// proj: blocks [0, PROJ_BLOCKS): 128 rows x 128 cols x 3 mats per block,
//       A-fragments (h rows, fp32->bf16 in-register) loaded ONCE, reused
//       across Q/K/V.  Q written fp32; K|V interleaved bf16 per node.
// scatter: blocks [PROJ_BLOCKS, ...): bump cursor, place src in dst-sorted
//       order.  After this kernel cursor[n] == row END of node n.
// ---------------------------------------------------------------------------
__global__ __launch_bounds__(256) void proj_scatter_kernel(
    const float* __restrict__ h,
    const unsigned short* __restrict__ Wt,
    const float* __restrict__ bq, const float* __restrict__ bk,
    const float* __restrict__ bv,
    const int* __restrict__ src, const int* __restrict__ dst,
    int* __restrict__ cursor,
    float* __restrict__ Qf, __hip_bfloat16* __restrict__ KV,
    int* __restrict__ sorted_src)
{
    const int bid = blockIdx.x;
    if (bid >= PROJ_BLOCKS) {
        const int e = (bid - PROJ_BLOCKS) * 256 + threadIdx.x;
        if (e < N_EDGES) {
            const int pos = atomicAdd(&cursor[dst[e]], 1);
            sorted_src[pos] = src[e];
        }
        return;
    }

    const int wave = threadIdx.x >> 6;
    const int lane = threadIdx.x & 63;
    const int quad = lane >> 4;
    const int l16  = lane & 15;
    const int rowBase = bid * 128 + wave * 32;

    int r0 = rowBase + l16;       if (r0 >= N_NODES) r0 = N_NODES - 1;
    int r1 = rowBase + 16 + l16;  if (r1 >= N_NODES) r1 = N_NODES - 1;

    // A fragments: load h rows (fp32) once, convert to bf16.
    short8 afr[2][4];
    #pragma unroll
    for (int kc = 0; kc < 4; ++kc) {
        const int ko = kc * 32 + quad * 8;
        afr[0][kc] = cvt8(h + (size_t)r0 * DIN + ko);
        afr[1][kc] = cvt8(h + (size_t)r1 * DIN + ko);
    }

    #pragma unroll
    for (int mat = 0; mat < 3; ++mat) {
        const unsigned short* wb = Wt + mat * (DIN * HD);
        const float* bias = (mat == 0) ? bq : (mat == 1) ? bk : bv;

        float4v acc[2][8];
        #pragma unroll
        for (int rt = 0; rt < 2; ++rt)
            #pragma unroll
            for (int ct = 0; ct < 8; ++ct)
                acc[rt][ct] = (float4v){0.f, 0.f, 0.f, 0.f};

        #pragma unroll
        for (int kc = 0; kc < 4; ++kc) {
            const int ko = kc * 32 + quad * 8;
            #pragma unroll
            for (int ct = 0; ct < 8; ++ct) {
                const short8 b = *(const short8*)(wb + (ct * 16 + l16) * DIN + ko);
                acc[0][ct] = __builtin_amdgcn_mfma_f32_16x16x32_bf16(afr[0][kc], b, acc[0][ct], 0, 0, 0);
                acc[1][ct] = __builtin_amdgcn_mfma_f32_16x16x32_bf16(afr[1][kc], b, acc[1][ct], 0, 0, 0);
            }
        }

        #pragma unroll
        for (int ct = 0; ct < 8; ++ct) {
            const int col = ct * 16 + l16;
            const float bcol = bias[col];
            #pragma unroll
            for (int rt = 0; rt < 2; ++rt) {
                #pragma unroll
                for (int r = 0; r < 4; ++r) {
                    const int row = rowBase + rt * 16 + quad * 4 + r;
                    if (row < N_NODES) {
                        const float v = acc[rt][ct][r] + bcol;
                        if (mat == 0)
                            Qf[(size_t)row * HD + col] = v;
                        else
                            KV[(size_t)row * 256 + (mat == 2 ? 128 : 0) + col] =
                                __float2bfloat16(v);
                    }
                }
            }
        }
    }
}

// ---------------------------------------------------------------------------
// Node 5: aggregate.  One 128-thread block per destination node; edges in
// batches of 16.  Phase A: thread=(edge j, head h) computes the 16-elem dot
// ONCE (fp32 Q in registers, bf16 K gather), one exp per score -> LDS.
// Phase B: thread=(h,d) does V-gather fma with LDS score broadcast.
// ---------------------------------------------------------------------------
__global__ __launch_bounds__(128) void aggregate_kernel(
    const float* __restrict__ Qf, const __hip_bfloat16* __restrict__ KV,
    const int* __restrict__ cursor, const int* __restrict__ counts,
    const int* __restrict__ sorted_src, float* __restrict__ out)
{
    const int node = blockIdx.x;
    const int t    = threadIdx.x;
    const int end  = cursor[node];
    const int beg  = end - counts[node];

    const int jA = t >> 3;     // edge slot in batch (0..15)
    const int hA = t & 7;      // head for phase A
    const int hB = t >> 4;     // head for phase B

    __shared__ float sc_s[16][8];
    __shared__ int   s_s[16];

    // Q segment for this thread's phase-A head, held in registers.
    const float* qseg = Qf + (size_t)node * HD + hA * 16;
    const float4 q0 = *(const float4*)(qseg);
    const float4 q1 = *(const float4*)(qseg + 4);
    const float4 q2 = *(const float4*)(qseg + 8);
    const float4 q3 = *(const float4*)(qseg + 12);

    const short* kvb  = (const short*)KV;
    const short* vbase = kvb + 128 + t;

    float acc = 0.f, zacc = 0.f;

    for (int e0 = beg; e0 < end; e0 += 16) {
        const int nb = min(16, end - e0);

        if (jA < nb) {
            const int s = sorted_src[e0 + jA];
            if (hA == 0) s_s[jA] = s;
            const short* kp = kvb + (size_t)s * 256 + hA * 16;
            const short8 k0 = *(const short8*)kp;
            const short8 k1 = *(const short8*)(kp + 8);
            float dot;
            dot  = q0.x * bfb(k0[0]) + q0.y * bfb(k0[1])
                 + q0.z * bfb(k0[2]) + q0.w * bfb(k0[3]);
            dot += q1.x * bfb(k0[4]) + q1.y * bfb(k0[5])
                 + q1.z * bfb(k0[6]) + q1.w * bfb(k0[7]);
            dot += q2.x * bfb(k1[0]) + q2.y * bfb(k1[1])
                 + q2.z * bfb(k1[2]) + q2.w * bfb(k1[3]);
            dot += q3.x * bfb(k1[4]) + q3.y * bfb(k1[5])
                 + q3.z * bfb(k1[6]) + q3.w * bfb(k1[7]);
            sc_s[jA][hA] = __expf(fminf(fmaxf(dot * 0.25f, -5.f), 5.f));
        }
        __syncthreads();

        int j = 0;
        for (; j + 3 < nb; j += 4) {
            const int s0 = s_s[j],     s1 = s_s[j + 1];
            const int s2 = s_s[j + 2], s3 = s_s[j + 3];
            const float c0 = sc_s[j][hB],     c1 = sc_s[j + 1][hB];
            const float c2 = sc_s[j + 2][hB], c3 = sc_s[j + 3][hB];
            const float v0 = bfb(vbase[(size_t)s0 * 256]);
            const float v1 = bfb(vbase[(size_t)s1 * 256]);
            const float v2 = bfb(vbase[(size_t)s2 * 256]);
            const float v3 = bfb(vbase[(size_t)s3 * 256]);
            acc = fmaf(v0, c0, acc); acc = fmaf(v1, c1, acc);
            acc = fmaf(v2, c2, acc); acc = fmaf(v3, c3, acc);
            zacc += (c0 + c1) + (c2 + c3);
        }
        for (; j < nb; ++j) {
            const int s0 = s_s[j];
            const float c0 = sc_s[j][hB];
            acc = fmaf(bfb(vbase[(size_t)s0 * 256]), c0, acc);
            zacc += c0;
        }
        __syncthreads();
    }

    out[(size_t)node * HD + t] = acc / (zacc + 1e-6f);
}

// ---------------------------------------------------------------------------
extern "C" void kernel_launch(void* const* d_in, const int* in_sizes, int n_in,
                              void* d_out, int out_size, void* d_ws, size_t ws_size,
                              hipStream_t stream)
{
    const float* h   = (const float*)d_in[0];
    const float* Wq  = (const float*)d_in[1];
    const float* bq  = (const float*)d_in[2];
    const float* Wk  = (const float*)d_in[3];
    const float* bk  = (const float*)d_in[4];
    const float* Wv  = (const float*)d_in[5];
    const float* bv  = (const float*)d_in[6];
    const int*   src = (const int*)d_in[7];
    const int*   dst = (const int*)d_in[8];
    float* out = (float*)d_out;

    // workspace layout (16B-aligned segments):
    //   Qf fp32 [50000][128]            25.6 MB
    //   KV bf16 [50000][K128|V128]      25.6 MB
    //   Wt bf16 [3][128][128]            0.1 MB
    //   counts / cursor int [50176]      0.4 MB
    //   sorted_src int [800000]          3.2 MB
    float* Qf = (float*)d_ws;
    __hip_bfloat16* KV = (__hip_bfloat16*)(Qf + (size_t)N_NODES * HD);
    unsigned short* Wt = (unsigned short*)(KV + (size_t)N_NODES * 256);
    int* counts     = (int*)(Wt + 3 * DIN * HD);
    int* cursor     = counts + M_PAD;
    int* sorted_src = cursor + M_PAD;

    hipMemsetAsync(counts, 0, M_PAD * sizeof(int), stream);

    hist_cvtw_kernel<<<HIST_BLOCKS + CVTW_BLOCKS, 256, 0, stream>>>(
        dst, Wq, Wk, Wv, counts, Wt);

    scan_kernel<<<1, 1024, 0, stream>>>(counts, cursor);

    proj_scatter_kernel<<<PROJ_BLOCKS + SCAT_BLOCKS, 256, 0, stream>>>(
        h, Wt, bq, bk, bv, src, dst, cursor, Qf, KV, sorted_src);

    aggregate_kernel<<<N_NODES, 128, 0, stream>>>(
        Qf, KV, cursor, counts, sorted_src, out);
}